// Round 1
// baseline (319.782 us; speedup 1.0000x reference)
//
#include <hip/hip_runtime.h>
#include <hip/hip_bf16.h>

// Problem constants (fixed by reference)
#define N_B 4
#define NV 4096
#define NE 2048
#define NC 64   // C_IN == C_OUT == 64

// ---------------------------------------------------------------------------
// Kernel 1: Y[n,v,c] = sum_k x[n,v,k] * theta[k,c]
// grid = N*V/4 blocks of 256 threads (4 rows per block)
// ---------------------------------------------------------------------------
__global__ __launch_bounds__(256) void k_xtheta(const float* __restrict__ x,
                                                const float* __restrict__ th,
                                                float* __restrict__ Y) {
    __shared__ float ths[64][64];   // [k][c]
    __shared__ float xs[4][64];     // [row][k]
    const int t = threadIdx.x;

    // load theta (4096 floats = 1024 float4, 4 per thread)
    const float4* tsrc = reinterpret_cast<const float4*>(th);
    float4* tdst = reinterpret_cast<float4*>(&ths[0][0]);
#pragma unroll
    for (int i = 0; i < 4; ++i) tdst[t + i * 256] = tsrc[t + i * 256];

    const size_t row0 = (size_t)blockIdx.x * 4;   // global row index (n*V+v)
    xs[t >> 6][t & 63] = x[row0 * 64 + t];        // 4 rows x 64, coalesced
    __syncthreads();

    const int r = t >> 6;   // 0..3
    const int c = t & 63;   // 0..63
    float acc = 0.f;
#pragma unroll
    for (int k = 0; k < 64; ++k) acc += xs[r][k] * ths[k][c];
    Y[row0 * 64 + t] = acc;
}

// ---------------------------------------------------------------------------
// Kernel 2: vertex -> edge.
//   Y2[n,e,c] = (1/deg_e) * sum_v H[n,v,e] * Y[n,v,c]
//   deg_e = sum_v H[n,v,e]  (folded: every thread accumulates dsum)
// Tile: 32 e x 64 c per block, K-step = 64 v. grid = (E/32, N) = (64,4).
// ---------------------------------------------------------------------------
__global__ __launch_bounds__(256) void k_v2e(const float* __restrict__ H,
                                             const float* __restrict__ Y,
                                             float* __restrict__ Y2) {
    __shared__ float Ht[64][32];    // [v_local][e_local] -- reads stride-1, no pad needed
    __shared__ float Yt[64][64];    // [v_local][c]

    const int n  = blockIdx.y;
    const int e0 = blockIdx.x * 32;
    const int t  = threadIdx.x;
    const int e_local = t & 31;
    const int cb = (t >> 5) * 8;    // 8 consecutive c per thread

    const float* Hn = H + (size_t)n * NV * NE;
    const float* Yn = Y + (size_t)n * NV * NC;

    float acc[8] = {0, 0, 0, 0, 0, 0, 0, 0};
    float dsum = 0.f;

    for (int kk = 0; kk < NV; kk += 64) {
        __syncthreads();
        // load Ht: 64 rows x 32 floats = 512 float4, 2 per thread
#pragma unroll
        for (int i = 0; i < 2; ++i) {
            const int idx = t + i * 256;       // 0..511
            const int row = idx >> 3;          // 8 float4 per row
            const int q   = idx & 7;
            const float4 hv = *reinterpret_cast<const float4*>(
                Hn + (size_t)(kk + row) * NE + e0 + q * 4);
            *reinterpret_cast<float4*>(&Ht[row][q * 4]) = hv;
        }
        // load Yt: 64x64 floats = 1024 float4, 4 per thread (fully contiguous)
        const float4* ysrc = reinterpret_cast<const float4*>(Yn + (size_t)kk * NC);
        float4* ydst = reinterpret_cast<float4*>(&Yt[0][0]);
#pragma unroll
        for (int i = 0; i < 4; ++i) ydst[t + i * 256] = ysrc[t + i * 256];
        __syncthreads();

#pragma unroll
        for (int k = 0; k < 64; ++k) {
            const float h = Ht[k][e_local];
            dsum += h;
            const float4 y0 = *reinterpret_cast<const float4*>(&Yt[k][cb]);
            const float4 y1 = *reinterpret_cast<const float4*>(&Yt[k][cb + 4]);
            acc[0] += h * y0.x; acc[1] += h * y0.y;
            acc[2] += h * y0.z; acc[3] += h * y0.w;
            acc[4] += h * y1.x; acc[5] += h * y1.y;
            acc[6] += h * y1.z; acc[7] += h * y1.w;
        }
    }

    const float rde = 1.0f / dsum;   // deg >= 1 guaranteed by reference
    float4 o0 = make_float4(acc[0] * rde, acc[1] * rde, acc[2] * rde, acc[3] * rde);
    float4 o1 = make_float4(acc[4] * rde, acc[5] * rde, acc[6] * rde, acc[7] * rde);
    float* dst = Y2 + ((size_t)n * NE + e0 + e_local) * NC + cb;
    *reinterpret_cast<float4*>(dst)     = o0;
    *reinterpret_cast<float4*>(dst + 4) = o1;
}

// ---------------------------------------------------------------------------
// Kernel 3: edge -> vertex.
//   out[n,v,c] = (1/deg_v) * sum_e H[n,v,e] * Y2[n,e,c] + bias[c]
//   deg_v = sum_e H[n,v,e]  (folded)
// Tile: 32 v x 64 c per block, K-step = 64 e. grid = (V/32, N) = (128,4).
// ---------------------------------------------------------------------------
__global__ __launch_bounds__(256) void k_e2v(const float* __restrict__ H,
                                             const float* __restrict__ Y2,
                                             const float* __restrict__ bias,
                                             float* __restrict__ out) {
    __shared__ float Ht[32][65];    // [v_local][k], pad 65 -> bank = (v*65+k)%32 = (v+k)%32, conflict-free
    __shared__ float Y2t[64][64];   // [k][c]

    const int n  = blockIdx.y;
    const int v0 = blockIdx.x * 32;
    const int t  = threadIdx.x;
    const int v_local = t & 31;
    const int cb = (t >> 5) * 8;

    const float* Hn  = H  + (size_t)n * NV * NE;
    const float* Y2n = Y2 + (size_t)n * NE * NC;

    float acc[8] = {0, 0, 0, 0, 0, 0, 0, 0};
    float dsum = 0.f;

    for (int kk = 0; kk < NE; kk += 64) {
        __syncthreads();
        // load Ht: 32 rows x 64 floats = 2048 floats, 8 per thread.
        // Global read as 2x float4; LDS write scalar (row stride 65 breaks 16B align).
        {
            const int row = t >> 3;          // 0..31
            const int q   = (t & 7) * 8;     // 0..56
            const float* src = Hn + (size_t)(v0 + row) * NE + kk + q;
            const float4 a = *reinterpret_cast<const float4*>(src);
            const float4 b = *reinterpret_cast<const float4*>(src + 4);
            Ht[row][q + 0] = a.x; Ht[row][q + 1] = a.y;
            Ht[row][q + 2] = a.z; Ht[row][q + 3] = a.w;
            Ht[row][q + 4] = b.x; Ht[row][q + 5] = b.y;
            Ht[row][q + 6] = b.z; Ht[row][q + 7] = b.w;
        }
        // load Y2t: 64x64 floats flat contiguous
        const float4* ysrc = reinterpret_cast<const float4*>(Y2n + (size_t)kk * NC);
        float4* ydst = reinterpret_cast<float4*>(&Y2t[0][0]);
#pragma unroll
        for (int i = 0; i < 4; ++i) ydst[t + i * 256] = ysrc[t + i * 256];
        __syncthreads();

#pragma unroll
        for (int k = 0; k < 64; ++k) {
            const float h = Ht[v_local][k];
            dsum += h;
            const float4 y0 = *reinterpret_cast<const float4*>(&Y2t[k][cb]);
            const float4 y1 = *reinterpret_cast<const float4*>(&Y2t[k][cb + 4]);
            acc[0] += h * y0.x; acc[1] += h * y0.y;
            acc[2] += h * y0.z; acc[3] += h * y0.w;
            acc[4] += h * y1.x; acc[5] += h * y1.y;
            acc[6] += h * y1.z; acc[7] += h * y1.w;
        }
    }

    const float rdv = 1.0f / dsum;
    float* dst = out + ((size_t)n * NV + v0 + v_local) * NC + cb;
    float4 o0 = make_float4(acc[0] * rdv + bias[cb + 0],
                            acc[1] * rdv + bias[cb + 1],
                            acc[2] * rdv + bias[cb + 2],
                            acc[3] * rdv + bias[cb + 3]);
    float4 o1 = make_float4(acc[4] * rdv + bias[cb + 4],
                            acc[5] * rdv + bias[cb + 5],
                            acc[6] * rdv + bias[cb + 6],
                            acc[7] * rdv + bias[cb + 7]);
    *reinterpret_cast<float4*>(dst)     = o0;
    *reinterpret_cast<float4*>(dst + 4) = o1;
}

// ---------------------------------------------------------------------------
extern "C" void kernel_launch(void* const* d_in, const int* in_sizes, int n_in,
                              void* d_out, int out_size, void* d_ws, size_t ws_size,
                              hipStream_t stream) {
    const float* x     = (const float*)d_in[0];   // [N,V,64]
    const float* H     = (const float*)d_in[1];   // [N,V,E]
    const float* theta = (const float*)d_in[2];   // [64,64]
    const float* bias  = (const float*)d_in[3];   // [64]
    float* out = (float*)d_out;                   // [N,V,64]

    // workspace: Y [N,V,64] then Y2 [N,E,64]   (4 MB + 2 MB)
    float* Y  = (float*)d_ws;
    float* Y2 = Y + (size_t)N_B * NV * NC;

    k_xtheta<<<dim3(N_B * NV / 4), 256, 0, stream>>>(x, theta, Y);
    k_v2e<<<dim3(NE / 32, N_B), 256, 0, stream>>>(H, Y, Y2);
    k_e2v<<<dim3(NV / 32, N_B), 256, 0, stream>>>(H, Y2, bias, out);
}

// Round 2
// 290.808 us; speedup vs baseline: 1.0996x; 1.0996x over previous
//
#include <hip/hip_runtime.h>
#include <hip/hip_bf16.h>

// Problem constants (fixed by reference)
#define N_B 4
#define NV 4096
#define NE 2048
#define NC 64   // C_IN == C_OUT == 64

// ---------------------------------------------------------------------------
// Kernel 1: Y[n,v,c] = sum_k x[n,v,k] * theta[k,c]
// ---------------------------------------------------------------------------
__global__ __launch_bounds__(256) void k_xtheta(const float* __restrict__ x,
                                                const float* __restrict__ th,
                                                float* __restrict__ Y) {
    __shared__ float ths[64][64];   // [k][c]
    __shared__ float xs[4][64];     // [row][k]
    const int t = threadIdx.x;

    const float4* tsrc = reinterpret_cast<const float4*>(th);
    float4* tdst = reinterpret_cast<float4*>(&ths[0][0]);
#pragma unroll
    for (int i = 0; i < 4; ++i) tdst[t + i * 256] = tsrc[t + i * 256];

    const size_t row0 = (size_t)blockIdx.x * 4;
    xs[t >> 6][t & 63] = x[row0 * 64 + t];
    __syncthreads();

    const int r = t >> 6;
    const int c = t & 63;
    float acc = 0.f;
#pragma unroll
    for (int k = 0; k < 64; ++k) acc += xs[r][k] * ths[k][c];
    Y[row0 * 64 + t] = acc;
}

// ---------------------------------------------------------------------------
// Kernel 2: vertex -> edge partials.
//   Y2acc[n,e,c] += sum_{v in Krange} H[n,v,e] * Y[n,v,c]    (atomic)
//   de[n,e]      += sum_{v in Krange} H[n,v,e]               (atomic, exact ints)
// Tile: 64 e x 64 c, K-split 16 (Krange=256, 8 staging steps of 32).
// grid = (NE/64, 16, N) = (32,16,4) = 2048 blocks -> 8 blocks/CU, 32 waves/CU.
// Per thread: 4e x 4c outer product -> 16 FMA per 2 ds_read_b128.
// ---------------------------------------------------------------------------
__global__ __launch_bounds__(256, 8) void k_v2e(const float* __restrict__ H,
                                                const float* __restrict__ Y,
                                                float* __restrict__ Y2acc,
                                                float* __restrict__ de) {
    __shared__ float Ht[32][64];    // [v_local][e_local]
    __shared__ float Yt[32][64];    // [v_local][c]

    const int n   = blockIdx.z;
    const int e0  = blockIdx.x * 64;
    const int kk0 = blockIdx.y * (NV / 16);   // 256-row K range
    const int t   = threadIdx.x;
    const int e4  = (t & 15) * 4;
    const int c4  = (t >> 4) * 4;

    const float* Hn = H + (size_t)n * NV * NE;
    const float* Yn = Y + (size_t)n * NV * NC;

    float acc[4][4] = {};
    float dsum[4] = {0.f, 0.f, 0.f, 0.f};

    for (int s = 0; s < 8; ++s) {
        const int v0 = kk0 + s * 32;
        __syncthreads();
        // stage H: 32 rows x 64 floats = 512 float4, 2/thread, coalesced
#pragma unroll
        for (int i = 0; i < 2; ++i) {
            const int idx = i * 256 + t;
            const int row = idx >> 4;
            const int q   = idx & 15;
            *reinterpret_cast<float4*>(&Ht[row][q * 4]) =
                *reinterpret_cast<const float4*>(Hn + (size_t)(v0 + row) * NE + e0 + q * 4);
        }
        // stage Y: 32x64 slab is fully contiguous in memory
        {
            const float4* ys = reinterpret_cast<const float4*>(Yn + (size_t)v0 * NC);
            float4* yd = reinterpret_cast<float4*>(&Yt[0][0]);
#pragma unroll
            for (int i = 0; i < 2; ++i) yd[i * 256 + t] = ys[i * 256 + t];
        }
        __syncthreads();

#pragma unroll
        for (int k = 0; k < 32; ++k) {
            const float4 h = *reinterpret_cast<const float4*>(&Ht[k][e4]);
            const float4 y = *reinterpret_cast<const float4*>(&Yt[k][c4]);
            dsum[0] += h.x; dsum[1] += h.y; dsum[2] += h.z; dsum[3] += h.w;
            acc[0][0] += h.x * y.x; acc[0][1] += h.x * y.y; acc[0][2] += h.x * y.z; acc[0][3] += h.x * y.w;
            acc[1][0] += h.y * y.x; acc[1][1] += h.y * y.y; acc[1][2] += h.y * y.z; acc[1][3] += h.y * y.w;
            acc[2][0] += h.z * y.x; acc[2][1] += h.z * y.y; acc[2][2] += h.z * y.z; acc[2][3] += h.z * y.w;
            acc[3][0] += h.w * y.x; acc[3][1] += h.w * y.y; acc[3][2] += h.w * y.z; acc[3][3] += h.w * y.w;
        }
    }

    float* base = Y2acc + ((size_t)n * NE + e0 + e4) * NC + c4;
#pragma unroll
    for (int i = 0; i < 4; ++i)
#pragma unroll
        for (int j = 0; j < 4; ++j)
            atomicAdd(base + (size_t)i * NC + j, acc[i][j]);

    if (c4 == 0) {
#pragma unroll
        for (int i = 0; i < 4; ++i) atomicAdd(de + n * NE + e0 + e4 + i, dsum[i]);
    }
}

// ---------------------------------------------------------------------------
// Kernel 3: edge -> vertex partials.
//   out[n,v,c] += sum_{e in Krange} H[n,v,e] * (Y2acc[n,e,c]/de[n,e])  (atomic)
//   dv[n,v]    += sum_{e in Krange} H[n,v,e]                           (atomic)
// Tile: 64 v x 64 c, K-split 8 (Krange=256, 8 steps of 32).
// grid = (NV/64, 8, N) = (64,8,4) = 2048 blocks.
// H is staged TRANSPOSED so the k-loop reads it as b128 rows.
// ---------------------------------------------------------------------------
__global__ __launch_bounds__(256, 8) void k_e2v(const float* __restrict__ H,
                                                const float* __restrict__ Y2,
                                                const float* __restrict__ de,
                                                float* __restrict__ dv,
                                                float* __restrict__ out) {
    __shared__ float Ht[32][68];    // [e_local][v_local], pad 68 (16B-aligned rows)
    __shared__ float Yt[32][64];    // [e_local][c], pre-scaled by 1/de

    const int n   = blockIdx.z;
    const int v0  = blockIdx.x * 64;
    const int kk0 = blockIdx.y * (NE / 8);    // 256-col K range
    const int t   = threadIdx.x;
    const int v4  = (t & 15) * 4;
    const int c4  = (t >> 4) * 4;

    const float* Hn  = H  + (size_t)n * NV * NE;
    const float* Y2n = Y2 + (size_t)n * NE * NC;
    const float* den = de + n * NE;

    float acc[4][4] = {};
    float dsum[4] = {0.f, 0.f, 0.f, 0.f};

    for (int s = 0; s < 8; ++s) {
        const int ek = kk0 + s * 32;
        __syncthreads();
        // stage H transposed: 64 v-rows x 32 e = 512 float4 reads, 2/thread,
        // scalar LDS writes (4-way bank conflict, amortized over the k-loop)
#pragma unroll
        for (int i = 0; i < 2; ++i) {
            const int idx = i * 256 + t;
            const int row = idx >> 3;       // v_local 0..63
            const int q   = idx & 7;        // which float4 within the 32-e strip
            const float4 hv = *reinterpret_cast<const float4*>(
                Hn + (size_t)(v0 + row) * NE + ek + q * 4);
            Ht[q * 4 + 0][row] = hv.x;
            Ht[q * 4 + 1][row] = hv.y;
            Ht[q * 4 + 2][row] = hv.z;
            Ht[q * 4 + 3][row] = hv.w;
        }
        // stage Y2 scaled by 1/de: 32 rows x 64 = 512 float4, 2/thread
#pragma unroll
        for (int i = 0; i < 2; ++i) {
            const int idx = i * 256 + t;
            const int row = idx >> 4;
            const int q   = idx & 15;
            const float rde = 1.0f / den[ek + row];   // exact integer degree
            float4 y = *reinterpret_cast<const float4*>(Y2n + (size_t)(ek + row) * NC + q * 4);
            y.x *= rde; y.y *= rde; y.z *= rde; y.w *= rde;
            *reinterpret_cast<float4*>(&Yt[row][q * 4]) = y;
        }
        __syncthreads();

#pragma unroll
        for (int k = 0; k < 32; ++k) {
            const float4 h = *reinterpret_cast<const float4*>(&Ht[k][v4]);
            const float4 y = *reinterpret_cast<const float4*>(&Yt[k][c4]);
            dsum[0] += h.x; dsum[1] += h.y; dsum[2] += h.z; dsum[3] += h.w;
            acc[0][0] += h.x * y.x; acc[0][1] += h.x * y.y; acc[0][2] += h.x * y.z; acc[0][3] += h.x * y.w;
            acc[1][0] += h.y * y.x; acc[1][1] += h.y * y.y; acc[1][2] += h.y * y.z; acc[1][3] += h.y * y.w;
            acc[2][0] += h.z * y.x; acc[2][1] += h.z * y.y; acc[2][2] += h.z * y.z; acc[2][3] += h.z * y.w;
            acc[3][0] += h.w * y.x; acc[3][1] += h.w * y.y; acc[3][2] += h.w * y.z; acc[3][3] += h.w * y.w;
        }
    }

    float* base = out + ((size_t)n * NV + v0 + v4) * NC + c4;
#pragma unroll
    for (int i = 0; i < 4; ++i)
#pragma unroll
        for (int j = 0; j < 4; ++j)
            atomicAdd(base + (size_t)i * NC + j, acc[i][j]);

    if (c4 == 0) {
#pragma unroll
        for (int i = 0; i < 4; ++i) atomicAdd(dv + n * NV + v0 + v4 + i, dsum[i]);
    }
}

// ---------------------------------------------------------------------------
// Kernel 4: out = out * (1/dv) + bias   (in-place over d_out)
// ---------------------------------------------------------------------------
__global__ __launch_bounds__(256) void k_finish(float* __restrict__ out,
                                                const float* __restrict__ dv,
                                                const float* __restrict__ bias) {
    const int i = blockIdx.x * 256 + threadIdx.x;    // float4 index, 262144 total
    const float rdv = 1.0f / dv[i >> 4];             // global row = (4i)/64
    const int c = (i & 15) * 4;
    float4 v = reinterpret_cast<float4*>(out)[i];
    const float4 b = *reinterpret_cast<const float4*>(&bias[c]);
    v.x = v.x * rdv + b.x;
    v.y = v.y * rdv + b.y;
    v.z = v.z * rdv + b.z;
    v.w = v.w * rdv + b.w;
    reinterpret_cast<float4*>(out)[i] = v;
}

// ---------------------------------------------------------------------------
extern "C" void kernel_launch(void* const* d_in, const int* in_sizes, int n_in,
                              void* d_out, int out_size, void* d_ws, size_t ws_size,
                              hipStream_t stream) {
    const float* x     = (const float*)d_in[0];   // [N,V,64]
    const float* H     = (const float*)d_in[1];   // [N,V,E]
    const float* theta = (const float*)d_in[2];   // [64,64]
    const float* bias  = (const float*)d_in[3];   // [64]
    float* out = (float*)d_out;                   // [N,V,64]

    // ws layout: Y 4MB | Y2acc 2MB | de 32KB | dv 64KB   (~6.1 MB)
    float* Y     = (float*)d_ws;
    float* Y2acc = Y + (size_t)N_B * NV * NC;
    float* de    = Y2acc + (size_t)N_B * NE * NC;
    float* dv    = de + (size_t)N_B * NE;

    // zero atomic accumulators (async memset is graph-capturable)
    hipMemsetAsync(Y2acc, 0, (size_t)N_B * NE * NC * sizeof(float), stream);
    hipMemsetAsync(de,    0, (size_t)N_B * NE * sizeof(float), stream);
    hipMemsetAsync(dv,    0, (size_t)N_B * NV * sizeof(float), stream);
    hipMemsetAsync(out,   0, (size_t)N_B * NV * NC * sizeof(float), stream);

    k_xtheta<<<dim3(N_B * NV / 4), 256, 0, stream>>>(x, theta, Y);
    k_v2e<<<dim3(NE / 64, 16, N_B), 256, 0, stream>>>(H, Y, Y2acc, de);
    k_e2v<<<dim3(NV / 64, 8, N_B), 256, 0, stream>>>(H, Y2acc, de, dv, out);
    k_finish<<<dim3(N_B * NV * NC / 4 / 256), 256, 0, stream>>>(out, dv, bias);
}